// Round 1
// baseline (1455.101 us; speedup 1.0000x reference)
//
#include <hip/hip_runtime.h>

#define IN_F 128
#define OUT_F 128

// ---------------------------------------------------------------------------
// Kernel 1: support = X @ W   (fp32, tiled LDS GEMM — no fp32 MFMA on CDNA4)
// Block: 256 threads -> 32 rows x 128 cols of output.
// Thread t: jq = t&31 (col float4), rg = t>>5 (row group of 4 rows, stride 8).
// ---------------------------------------------------------------------------
__global__ __launch_bounds__(256) void gemm_xw(const float* __restrict__ x,
                                               const float* __restrict__ w,
                                               float* __restrict__ support,
                                               int n) {
  __shared__ float xs[32][33];    // +1 pad
  __shared__ float ws[32][128];   // K-tile of W: 16 KB
  const int tid = threadIdx.x;
  const int jq  = tid & 31;
  const int rg  = tid >> 5;
  const int row0 = blockIdx.x * 32;

  float4 acc[4];
#pragma unroll
  for (int i = 0; i < 4; ++i) acc[i] = make_float4(0.f, 0.f, 0.f, 0.f);

  for (int k0 = 0; k0 < IN_F; k0 += 32) {
    // Load W tile [32 k][128 j]: 1024 float4, 4 per thread, coalesced.
#pragma unroll
    for (int i = 0; i < 4; ++i) {
      int idx = tid + i * 256;
      int kk  = idx >> 5;
      int qq  = idx & 31;
      float4 v = ((const float4*)(w + (size_t)(k0 + kk) * OUT_F))[qq];
      *(float4*)&ws[kk][qq * 4] = v;
    }
    // Load X tile [32 rows][32 k]: one float4 per thread, coalesced.
    {
      int rr = tid >> 3;
      int qq = tid & 7;
      int grow = row0 + rr;
      float4 v = make_float4(0.f, 0.f, 0.f, 0.f);
      if (grow < n) v = ((const float4*)(x + (size_t)grow * IN_F + k0))[qq];
      xs[rr][qq * 4 + 0] = v.x;
      xs[rr][qq * 4 + 1] = v.y;
      xs[rr][qq * 4 + 2] = v.z;
      xs[rr][qq * 4 + 3] = v.w;
    }
    __syncthreads();
#pragma unroll
    for (int kk = 0; kk < 32; ++kk) {
      float4 wv = *(const float4*)&ws[kk][jq * 4];
#pragma unroll
      for (int rr = 0; rr < 4; ++rr) {
        float xv = xs[rg + rr * 8][kk];
        acc[rr].x = fmaf(xv, wv.x, acc[rr].x);
        acc[rr].y = fmaf(xv, wv.y, acc[rr].y);
        acc[rr].z = fmaf(xv, wv.z, acc[rr].z);
        acc[rr].w = fmaf(xv, wv.w, acc[rr].w);
      }
    }
    __syncthreads();
  }
#pragma unroll
  for (int rr = 0; rr < 4; ++rr) {
    int grow = row0 + rg + rr * 8;
    if (grow < n) ((float4*)(support + (size_t)grow * OUT_F))[jq] = acc[rr];
  }
}

// ---------------------------------------------------------------------------
// Kernel 2: out[n][f] = bias[f]   (d_out is poisoned 0xAA before every launch)
// ---------------------------------------------------------------------------
__global__ __launch_bounds__(256) void init_out(float* __restrict__ out,
                                                const float* __restrict__ bias,
                                                int n_nodes) {
  int idx = blockIdx.x * 256 + threadIdx.x;          // float4 index
  int total = n_nodes * (OUT_F / 4);
  if (idx < total) {
    int q = idx & (OUT_F / 4 - 1);
    ((float4*)out)[idx] = ((const float4*)bias)[q];
  }
}

// ---------------------------------------------------------------------------
// Kernel 3: edge-parallel scatter: out[row[e]] += val[e] * support[col[e]]
// 32 lanes per edge, float4 per lane -> 512 B contiguous gather per edge.
// unsafeAtomicAdd -> hardware global_atomic_add_f32 (no CAS loop, no return).
// ---------------------------------------------------------------------------
__global__ __launch_bounds__(256) void spmm_atomic(const int* __restrict__ erow,
                                                   const int* __restrict__ ecol,
                                                   const float* __restrict__ eval_,
                                                   const float* __restrict__ support,
                                                   float* __restrict__ out,
                                                   int n_edges) {
  int t = blockIdx.x * 256 + threadIdx.x;
  int e = t >> 5;
  int q = t & 31;
  if (e < n_edges) {
    int r = erow[e];
    int c = ecol[e];
    float v = eval_[e];
    float4 s = ((const float4*)support)[(size_t)c * (OUT_F / 4) + q];
    float* op = out + (size_t)r * OUT_F + q * 4;
    unsafeAtomicAdd(op + 0, v * s.x);
    unsafeAtomicAdd(op + 1, v * s.y);
    unsafeAtomicAdd(op + 2, v * s.z);
    unsafeAtomicAdd(op + 3, v * s.w);
  }
}

extern "C" void kernel_launch(void* const* d_in, const int* in_sizes, int n_in,
                              void* d_out, int out_size, void* d_ws, size_t ws_size,
                              hipStream_t stream) {
  const float* x     = (const float*)d_in[0];
  const int*   erow  = (const int*)d_in[1];
  const int*   ecol  = (const int*)d_in[2];
  const float* eval_ = (const float*)d_in[3];
  const float* w     = (const float*)d_in[4];
  const float* bias  = (const float*)d_in[5];
  float* out = (float*)d_out;

  const int n_nodes = in_sizes[0] / IN_F;
  const int n_edges = in_sizes[1];

  float* support = (float*)d_ws;   // n_nodes * OUT_F floats = 25.6 MB

  gemm_xw<<<(n_nodes + 31) / 32, 256, 0, stream>>>(x, w, support, n_nodes);

  int total_q = n_nodes * (OUT_F / 4);
  init_out<<<(total_q + 255) / 256, 256, 0, stream>>>(out, bias, n_nodes);

  long long threads = (long long)n_edges * 32;
  spmm_atomic<<<(int)((threads + 255) / 256), 256, 0, stream>>>(
      erow, ecol, eval_, support, out, n_edges);
}

// Round 2
// 266.340 us; speedup vs baseline: 5.4633x; 5.4633x over previous
//
#include <hip/hip_runtime.h>

#define IN_F 128
#define OUT_F 128

// ---------------------------------------------------------------------------
// Kernel 1: support = X @ W   (fp32, tiled LDS GEMM — no fp32 MFMA on CDNA4)
// ---------------------------------------------------------------------------
__global__ __launch_bounds__(256) void gemm_xw(const float* __restrict__ x,
                                               const float* __restrict__ w,
                                               float* __restrict__ support,
                                               int n) {
  __shared__ float xs[32][33];    // +1 pad
  __shared__ float ws[32][128];   // K-tile of W: 16 KB
  const int tid = threadIdx.x;
  const int jq  = tid & 31;
  const int rg  = tid >> 5;
  const int row0 = blockIdx.x * 32;

  float4 acc[4];
#pragma unroll
  for (int i = 0; i < 4; ++i) acc[i] = make_float4(0.f, 0.f, 0.f, 0.f);

  for (int k0 = 0; k0 < IN_F; k0 += 32) {
#pragma unroll
    for (int i = 0; i < 4; ++i) {
      int idx = tid + i * 256;
      int kk  = idx >> 5;
      int qq  = idx & 31;
      float4 v = ((const float4*)(w + (size_t)(k0 + kk) * OUT_F))[qq];
      *(float4*)&ws[kk][qq * 4] = v;
    }
    {
      int rr = tid >> 3;
      int qq = tid & 7;
      int grow = row0 + rr;
      float4 v = make_float4(0.f, 0.f, 0.f, 0.f);
      if (grow < n) v = ((const float4*)(x + (size_t)grow * IN_F + k0))[qq];
      xs[rr][qq * 4 + 0] = v.x;
      xs[rr][qq * 4 + 1] = v.y;
      xs[rr][qq * 4 + 2] = v.z;
      xs[rr][qq * 4 + 3] = v.w;
    }
    __syncthreads();
#pragma unroll
    for (int kk = 0; kk < 32; ++kk) {
      float4 wv = *(const float4*)&ws[kk][jq * 4];
#pragma unroll
      for (int rr = 0; rr < 4; ++rr) {
        float xv = xs[rg + rr * 8][kk];
        acc[rr].x = fmaf(xv, wv.x, acc[rr].x);
        acc[rr].y = fmaf(xv, wv.y, acc[rr].y);
        acc[rr].z = fmaf(xv, wv.z, acc[rr].z);
        acc[rr].w = fmaf(xv, wv.w, acc[rr].w);
      }
    }
    __syncthreads();
  }
#pragma unroll
  for (int rr = 0; rr < 4; ++rr) {
    int grow = row0 + rg + rr * 8;
    if (grow < n) ((float4*)(support + (size_t)grow * OUT_F))[jq] = acc[rr];
  }
}

// ---------------------------------------------------------------------------
// CSR build: zero -> histogram -> 3-kernel exclusive scan -> bucket scatter
// ---------------------------------------------------------------------------
__global__ __launch_bounds__(256) void zero_counts(int* __restrict__ counts, int L) {
  int i = blockIdx.x * 256 + threadIdx.x;
  if (i < L) counts[i] = 0;
}

__global__ __launch_bounds__(256) void hist_rows(const int* __restrict__ erow,
                                                 int* __restrict__ counts, int n_edges) {
  int e = blockIdx.x * 256 + threadIdx.x;
  if (e < n_edges) atomicAdd(&counts[erow[e]], 1);
}

// Hillis-Steele inclusive scan over 256 values in LDS; returns exclusive prefix,
// leaves inclusive total in sdata[255].
__device__ __forceinline__ int block_excl_scan_256(int v, int* sdata) {
  int t = threadIdx.x;
  sdata[t] = v;
  __syncthreads();
#pragma unroll
  for (int d = 1; d < 256; d <<= 1) {
    int add = (t >= d) ? sdata[t - d] : 0;
    __syncthreads();
    sdata[t] += add;
    __syncthreads();
  }
  return sdata[t] - v;
}

// chunk = 1024 elements per block (4/thread)
__global__ __launch_bounds__(256) void scan_chunks(const int* __restrict__ counts,
                                                   int* __restrict__ offsets,
                                                   int* __restrict__ partials, int L) {
  __shared__ int sdata[256];
  int t = threadIdx.x;
  int base = blockIdx.x * 1024 + t * 4;
  int a[4];
#pragma unroll
  for (int i = 0; i < 4; ++i) { int idx = base + i; a[i] = (idx < L) ? counts[idx] : 0; }
  int local = a[0] + a[1] + a[2] + a[3];
  int pre = block_excl_scan_256(local, sdata);
  int run = pre;
#pragma unroll
  for (int i = 0; i < 4; ++i) { int idx = base + i; if (idx < L) offsets[idx] = run; run += a[i]; }
  if (t == 255) partials[blockIdx.x] = pre + local;
}

__global__ __launch_bounds__(256) void scan_partials(int* __restrict__ partials, int nChunks) {
  __shared__ int sdata[256];
  int t = threadIdx.x;
  int v = (t < nChunks) ? partials[t] : 0;
  int pre = block_excl_scan_256(v, sdata);
  if (t < nChunks) partials[t] = pre;
}

__global__ __launch_bounds__(256) void add_partials(int* __restrict__ offsets,
                                                    const int* __restrict__ partials,
                                                    int* __restrict__ cursor,
                                                    int L, int n_nodes) {
  int i = blockIdx.x * 256 + threadIdx.x;
  if (i < L) {
    int v = offsets[i] + partials[i >> 10];
    offsets[i] = v;
    if (i < n_nodes) cursor[i] = v;
  }
}

__global__ __launch_bounds__(256) void scatter_edges(const int* __restrict__ erow,
                                                     const int* __restrict__ ecol,
                                                     const float* __restrict__ eval_,
                                                     int* __restrict__ cursor,
                                                     int2* __restrict__ sedge, int n_edges) {
  int e = blockIdx.x * 256 + threadIdx.x;
  if (e < n_edges) {
    int r = erow[e];
    int pos = atomicAdd(&cursor[r], 1);
    sedge[pos] = make_int2(ecol[e], __float_as_int(eval_[e]));
  }
}

// ---------------------------------------------------------------------------
// Gather: one wave (64 lanes) per destination row; float2/lane = 128 features.
// Register accumulation, single coalesced write, bias folded in.
// ---------------------------------------------------------------------------
__global__ __launch_bounds__(256) void gather_csr(const int* __restrict__ offsets,
                                                  const int2* __restrict__ sedge,
                                                  const float* __restrict__ support,
                                                  const float* __restrict__ bias,
                                                  float* __restrict__ out, int n_nodes) {
  int row  = (int)((blockIdx.x * 256 + threadIdx.x) >> 6);
  int lane = threadIdx.x & 63;
  if (row >= n_nodes) return;
  int start = __builtin_amdgcn_readfirstlane(offsets[row]);
  int end   = __builtin_amdgcn_readfirstlane(offsets[row + 1]);
  float2 acc = make_float2(0.f, 0.f);
  for (int j = start; j < end; ++j) {
    int2 cv = sedge[j];
    float v = __int_as_float(cv.y);
    float2 s = ((const float2*)support)[(size_t)cv.x * 64 + lane];
    acc.x = fmaf(v, s.x, acc.x);
    acc.y = fmaf(v, s.y, acc.y);
  }
  float2 b = ((const float2*)bias)[lane];
  acc.x += b.x;
  acc.y += b.y;
  ((float2*)out)[(size_t)row * 64 + lane] = acc;
}

extern "C" void kernel_launch(void* const* d_in, const int* in_sizes, int n_in,
                              void* d_out, int out_size, void* d_ws, size_t ws_size,
                              hipStream_t stream) {
  const float* x     = (const float*)d_in[0];
  const int*   erow  = (const int*)d_in[1];
  const int*   ecol  = (const int*)d_in[2];
  const float* eval_ = (const float*)d_in[3];
  const float* w     = (const float*)d_in[4];
  const float* bias  = (const float*)d_in[5];
  float* out = (float*)d_out;

  const int n_nodes = in_sizes[0] / IN_F;
  const int n_edges = in_sizes[1];
  const int L = n_nodes + 1;           // scan length (counts[n_nodes] = 0 pad)

  // Workspace carve-up (256 B aligned slices)
  char* ws = (char*)d_ws;
  size_t off = 0;
  auto carve = [&](size_t bytes) { void* p = ws + off; off = (off + bytes + 255) & ~(size_t)255; return p; };
  float* support  = (float*)carve((size_t)n_nodes * OUT_F * sizeof(float)); // 25.6 MB
  int*   counts   = (int*)  carve((size_t)L * sizeof(int));
  int*   offsets  = (int*)  carve((size_t)L * sizeof(int));
  int*   cursor   = (int*)  carve((size_t)n_nodes * sizeof(int));
  int*   partials = (int*)  carve(256 * sizeof(int));
  int2*  sedge    = (int2*) carve((size_t)n_edges * sizeof(int2));          // 6.4 MB

  const int nChunks = (L + 1023) / 1024;

  gemm_xw<<<(n_nodes + 31) / 32, 256, 0, stream>>>(x, w, support, n_nodes);

  zero_counts<<<(L + 255) / 256, 256, 0, stream>>>(counts, L);
  hist_rows<<<(n_edges + 255) / 256, 256, 0, stream>>>(erow, counts, n_edges);
  scan_chunks<<<nChunks, 256, 0, stream>>>(counts, offsets, partials, L);
  scan_partials<<<1, 256, 0, stream>>>(partials, nChunks);
  add_partials<<<(L + 255) / 256, 256, 0, stream>>>(offsets, partials, cursor, L, n_nodes);
  scatter_edges<<<(n_edges + 255) / 256, 256, 0, stream>>>(erow, ecol, eval_, cursor, sedge, n_edges);

  gather_csr<<<(n_nodes + 3) / 4, 256, 0, stream>>>(offsets, sedge, support, bias, out, n_nodes);
}